// Round 3
// baseline (116.438 us; speedup 1.0000x reference)
//
#include <hip/hip_runtime.h>

// Problem: N=512, D=512, all fp32.
// pre_i[i,h] = sum_d he[i,d] * W0[h, d]        (NT gemm, h<512)
// pre_j[j,h] = sum_d he[j,d] * W0[h, 512+d]
// p[i,j] = sum_h relu(pre_i[i,h] + pre_j[j,h] + b0[h]) * w1[h]  (W1_b dropped: softmax-invariant)
// out = softmax_rows(p) @ h_e
//
// ws layout (floats): Cpart[2][512][1024] | Ppart[16][512][512] | Aw[512][512]

typedef float v2f __attribute__((ext_vector_type(2)));

#define LDS_STRIDE 68   // 64 + 4 pad
#define AS_STRIDE 132   // 128 + 4 pad

// ---------------------------------------------------------------------------
// Kernel A: K-split NT GEMM  Cpart[s][i][c] = sum_{d in slice s} he[i,d] * W0[c&511, ofs(c)+d]
// grid (16 c-tiles, 8 i-tiles, 2 d-slices), block 256, 64x64 tile, BK=32, 4x4 micro (pk-packed)
__global__ __launch_bounds__(256) void k_pre(const float* __restrict__ he,
                                             const float* __restrict__ w0,
                                             float* __restrict__ Cpart) {
    const int tid = threadIdx.x;
    const int tx = tid & 15, ty = tid >> 4;
    const int c0 = blockIdx.x * 64;
    const int i0 = blockIdx.y * 64;
    const int kbase0 = blockIdx.z * 256;
    const int hrow0 = c0 & 511;
    const int dofs  = (c0 >= 512) ? 512 : 0;

    __shared__ float As[32 * LDS_STRIDE];  // [d][i]
    __shared__ float Bs[32 * LDS_STRIDE];  // [d][c]

    v2f acc2[4][2] = {};

    for (int kt = 0; kt < 8; ++kt) {
        const int kb = kbase0 + kt * 32;
        #pragma unroll
        for (int r = 0; r < 2; ++r) {
            int f = tid + r * 256;
            int row = f >> 3;
            int kc = (f & 7) * 4;
            const float4 a = *(const float4*)&he[(i0 + row) * 512 + kb + kc];
            As[(kc + 0) * LDS_STRIDE + row] = a.x;
            As[(kc + 1) * LDS_STRIDE + row] = a.y;
            As[(kc + 2) * LDS_STRIDE + row] = a.z;
            As[(kc + 3) * LDS_STRIDE + row] = a.w;
        }
        #pragma unroll
        for (int r = 0; r < 2; ++r) {
            int f = tid + r * 256;
            int row = f >> 3;
            int kc = (f & 7) * 4;
            const float4 b = *(const float4*)&w0[(hrow0 + row) * 1024 + dofs + kb + kc];
            Bs[(kc + 0) * LDS_STRIDE + row] = b.x;
            Bs[(kc + 1) * LDS_STRIDE + row] = b.y;
            Bs[(kc + 2) * LDS_STRIDE + row] = b.z;
            Bs[(kc + 3) * LDS_STRIDE + row] = b.w;
        }
        __syncthreads();
        #pragma unroll
        for (int k = 0; k < 32; ++k) {
            const float4 a = *(const float4*)&As[k * LDS_STRIDE + 4 * ty];
            const float4 b = *(const float4*)&Bs[k * LDS_STRIDE + 4 * tx];
            const v2f b01 = {b.x, b.y}, b23 = {b.z, b.w};
            const float av[4] = {a.x, a.y, a.z, a.w};
            #pragma unroll
            for (int ii = 0; ii < 4; ++ii) {
                v2f av2 = {av[ii], av[ii]};
                acc2[ii][0] = __builtin_elementwise_fma(av2, b01, acc2[ii][0]);
                acc2[ii][1] = __builtin_elementwise_fma(av2, b23, acc2[ii][1]);
            }
        }
        __syncthreads();
    }
    float* outp = Cpart + (size_t)blockIdx.z * 512 * 1024;
    #pragma unroll
    for (int ii = 0; ii < 4; ++ii) {
        float4 v = make_float4(acc2[ii][0].x, acc2[ii][0].y, acc2[ii][1].x, acc2[ii][1].y);
        *(float4*)&outp[(i0 + 4 * ty + ii) * 1024 + c0 + 4 * tx] = v;
    }
}

// ---------------------------------------------------------------------------
// Kernel B: Ppart[hs][i][j] = sum_{h in slice hs (32 wide)} relu(preI[i,h] + cj[j,h]) * w1[h]
// grid (8 j-tiles of 64, 4 i-tiles of 128, 16 h-slices), block 256, micro 8i x 4j, pk-packed.
__global__ __launch_bounds__(256) void k_score(const float* __restrict__ Cpart,
                                               const float* __restrict__ b0,
                                               const float* __restrict__ w1,
                                               float* __restrict__ Ppart) {
    const int tid = threadIdx.x;
    const int tx = tid & 15, ty = tid >> 4;
    const int j0 = blockIdx.x * 64;
    const int i0 = blockIdx.y * 128;
    const int hb = blockIdx.z * 32;
    const float* C0 = Cpart;
    const float* C1 = Cpart + 512 * 1024;

    __shared__ float As[32 * AS_STRIDE];   // [h][i], 128 i + pad
    __shared__ float Bs[32 * LDS_STRIDE];  // [h][j], 64 j + pad
    __shared__ float Ws[32];

    v2f acc2[8][2] = {};

    // stage A: 128 i x 32 h (sum of the two d-slice partials)
    #pragma unroll
    for (int r = 0; r < 4; ++r) {
        int f = tid + r * 256;          // 0..1023
        int row = f >> 3;               // 0..127
        int hc = (f & 7) * 4;
        int g = (i0 + row) * 1024 + hb + hc;
        float4 a  = *(const float4*)&C0[g];
        float4 a1 = *(const float4*)&C1[g];
        As[(hc + 0) * AS_STRIDE + row] = a.x + a1.x;
        As[(hc + 1) * AS_STRIDE + row] = a.y + a1.y;
        As[(hc + 2) * AS_STRIDE + row] = a.z + a1.z;
        As[(hc + 3) * AS_STRIDE + row] = a.w + a1.w;
    }
    // stage B: 64 j x 32 h (+ bias)
    #pragma unroll
    for (int r = 0; r < 2; ++r) {
        int f = tid + r * 256;          // 0..511
        int row = f >> 3;               // 0..63
        int hc = (f & 7) * 4;
        int g = (j0 + row) * 1024 + 512 + hb + hc;
        float4 a  = *(const float4*)&C0[g];
        float4 a1 = *(const float4*)&C1[g];
        float4 bb = *(const float4*)&b0[hb + hc];
        Bs[(hc + 0) * LDS_STRIDE + row] = a.x + a1.x + bb.x;
        Bs[(hc + 1) * LDS_STRIDE + row] = a.y + a1.y + bb.y;
        Bs[(hc + 2) * LDS_STRIDE + row] = a.z + a1.z + bb.z;
        Bs[(hc + 3) * LDS_STRIDE + row] = a.w + a1.w + bb.w;
    }
    if (tid < 32) Ws[tid] = w1[hb + tid];
    __syncthreads();

    const v2f z2 = {0.0f, 0.0f};
    #pragma unroll
    for (int k = 0; k < 32; ++k) {
        const float4 alo = *(const float4*)&As[k * AS_STRIDE + 8 * ty];
        const float4 ahi = *(const float4*)&As[k * AS_STRIDE + 8 * ty + 4];
        const float4 b   = *(const float4*)&Bs[k * LDS_STRIDE + 4 * tx];
        const float w = Ws[k];
        const v2f w2 = {w, w};
        const v2f b01 = {b.x, b.y}, b23 = {b.z, b.w};
        const float av[8] = {alo.x, alo.y, alo.z, alo.w, ahi.x, ahi.y, ahi.z, ahi.w};
        #pragma unroll
        for (int ii = 0; ii < 8; ++ii) {
            v2f av2 = {av[ii], av[ii]};
            v2f x0 = av2 + b01;                         // v_pk_add_f32
            v2f x1 = av2 + b23;
            x0 = __builtin_elementwise_max(x0, z2);     // relu
            x1 = __builtin_elementwise_max(x1, z2);
            acc2[ii][0] = __builtin_elementwise_fma(x0, w2, acc2[ii][0]);  // v_pk_fma_f32
            acc2[ii][1] = __builtin_elementwise_fma(x1, w2, acc2[ii][1]);
        }
    }
    float* outp = Ppart + (size_t)blockIdx.z * 512 * 512;
    #pragma unroll
    for (int ii = 0; ii < 8; ++ii) {
        float4 v = make_float4(acc2[ii][0].x, acc2[ii][0].y, acc2[ii][1].x, acc2[ii][1].y);
        *(float4*)&outp[(i0 + 8 * ty + ii) * 512 + j0 + 4 * tx] = v;
    }
}

// ---------------------------------------------------------------------------
// Kernel C1: reduce 16 P-partials, row softmax -> Aw[i][j]. grid(512), block 256.
__global__ __launch_bounds__(256) void k_softmax(const float* __restrict__ Ppart,
                                                 float* __restrict__ Aw) {
    const int i = blockIdx.x;
    const int tid = threadIdx.x;
    float p0 = 0.f, p1 = 0.f;
    #pragma unroll
    for (int s = 0; s < 16; ++s) {
        p0 += Ppart[s * 262144 + i * 512 + tid];
        p1 += Ppart[s * 262144 + i * 512 + tid + 256];
    }
    __shared__ float red[256];
    red[tid] = fmaxf(p0, p1);
    __syncthreads();
    for (int s = 128; s > 0; s >>= 1) {
        if (tid < s) red[tid] = fmaxf(red[tid], red[tid + s]);
        __syncthreads();
    }
    const float m = red[0];
    __syncthreads();
    const float e0 = __expf(p0 - m);
    const float e1 = __expf(p1 - m);
    red[tid] = e0 + e1;
    __syncthreads();
    for (int s = 128; s > 0; s >>= 1) {
        if (tid < s) red[tid] += red[tid + s];
        __syncthreads();
    }
    const float inv = 1.0f / red[0];
    Aw[i * 512 + tid] = e0 * inv;
    Aw[i * 512 + tid + 256] = e1 * inv;
}

// ---------------------------------------------------------------------------
// Kernel C2: out = Aw @ h_e. grid (16 d-tiles, 16 i-tiles), block 256,
// 32x32 tile, BK=32, 2x2 micro (pk-packed).
__global__ __launch_bounds__(256) void k_out(const float* __restrict__ Aw,
                                             const float* __restrict__ he,
                                             float* __restrict__ outp) {
    const int tid = threadIdx.x;
    const int tx = tid & 15, ty = tid >> 4;
    const int d0 = blockIdx.x * 32;
    const int i0 = blockIdx.y * 32;
    __shared__ float As[32 * 34];  // [k][i]
    __shared__ float Bs[32 * 36];  // [k][d]
    v2f acc2[2] = {};
    for (int kt = 0; kt < 16; ++kt) {
        const int kb = kt * 32;
        {
            int row = tid >> 3;
            int kc = (tid & 7) * 4;
            float4 a = *(const float4*)&Aw[(i0 + row) * 512 + kb + kc];
            As[(kc + 0) * 34 + row] = a.x;
            As[(kc + 1) * 34 + row] = a.y;
            As[(kc + 2) * 34 + row] = a.z;
            As[(kc + 3) * 34 + row] = a.w;
        }
        {
            int row = tid >> 3;
            int dc = (tid & 7) * 4;
            *(float4*)&Bs[row * 36 + dc] = *(const float4*)&he[(kb + row) * 512 + d0 + dc];
        }
        __syncthreads();
        #pragma unroll
        for (int k = 0; k < 32; ++k) {
            const float2 a = *(const float2*)&As[k * 34 + 2 * ty];
            const float2 b = *(const float2*)&Bs[k * 36 + 2 * tx];
            const v2f b2 = {b.x, b.y};
            v2f a0 = {a.x, a.x}, a1 = {a.y, a.y};
            acc2[0] = __builtin_elementwise_fma(a0, b2, acc2[0]);
            acc2[1] = __builtin_elementwise_fma(a1, b2, acc2[1]);
        }
        __syncthreads();
    }
    #pragma unroll
    for (int ii = 0; ii < 2; ++ii) {
        float2 v = make_float2(acc2[ii].x, acc2[ii].y);
        *(float2*)&outp[(i0 + 2 * ty + ii) * 512 + d0 + 2 * tx] = v;
    }
}

extern "C" void kernel_launch(void* const* d_in, const int* in_sizes, int n_in,
                              void* d_out, int out_size, void* d_ws, size_t ws_size,
                              hipStream_t stream) {
    const float* he = (const float*)d_in[0];   // (512, 512)
    const float* w0 = (const float*)d_in[1];   // (512, 1024)
    const float* b0 = (const float*)d_in[2];   // (512,)
    const float* w1 = (const float*)d_in[3];   // (1, 512)
    // d_in[4] = W1_b: softmax-invariant, intentionally unused.
    float* outp = (float*)d_out;               // (512, 512)

    float* Cpart = (float*)d_ws;               // 2 * 512 * 1024
    float* Ppart = Cpart + 2 * 512 * 1024;     // 16 * 512 * 512
    float* Aw    = Ppart + 16 * 512 * 512;     // 512 * 512

    k_pre    <<<dim3(16, 8, 2), 256, 0, stream>>>(he, w0, Cpart);
    k_score  <<<dim3(8, 4, 16), 256, 0, stream>>>(Cpart, b0, w1, Ppart);
    k_softmax<<<dim3(512),      256, 0, stream>>>(Ppart, Aw);
    k_out    <<<dim3(16, 16),   256, 0, stream>>>(Aw, he, outp);
}